// Round 10
// baseline (1043.682 us; speedup 1.0000x reference)
//
#include <hip/hip_runtime.h>

#define D_MODEL 1024
#define NH 16
#define DK 64
#define DFF 4096
#define SEQ 2048
#define BATCH 4
#define NROWS (BATCH*SEQ)   // 8192
#define CHUNK 2048          // FFN row-chunk (16MB bf16 hidden fits dead k region)
#define NCHUNK (NROWS/CHUNK)

typedef short bf16x8 __attribute__((ext_vector_type(8)));
typedef float f32x4 __attribute__((ext_vector_type(4)));

__device__ __forceinline__ float bf2f(unsigned short u){
  union { float f; unsigned int i; } x; x.i = ((unsigned int)u) << 16; return x.f;
}
__device__ __forceinline__ unsigned short f2bf(float f){
  union { float f; unsigned int i; } x; x.f = f;
  unsigned int r = x.i + 0x7fffu + ((x.i >> 16) & 1u);
  return (unsigned short)(r >> 16);
}
__device__ __forceinline__ float fexp2(float x){
#if __has_builtin(__builtin_amdgcn_exp2f)
  return __builtin_amdgcn_exp2f(x);
#else
  return __exp2f(x);
#endif
}

// async global->LDS, 16B per lane (m97 pattern; LDS dest = wave base + lane*16)
__device__ __forceinline__ void gl_lds16(const void* g, void* l) {
  __builtin_amdgcn_global_load_lds((const __attribute__((address_space(1))) void*)g,
                                   (__attribute__((address_space(3))) void*)l, 16, 0, 0);
}

// T1 XCD-aware swizzle: hardware block hid lands on XCD hid%8; remap so each
// XCD gets a CONTIGUOUS logical chunk -> blocks sharing operand panels hit the
// same per-XCD L2. Bijective iff total % 8 == 0 (true at every call site).
// [R8 verified: attn FETCH_SIZE 139MB -> 24.7MB]
__device__ __forceinline__ int xcd_swz(int hid, int total) {
  return (hid & 7) * (total >> 3) + (hid >> 3);
}

// ---------------- fp32 -> bf16 bulk convert (weights) ----------------
__global__ __launch_bounds__(256) void cvt_f2b(const float* __restrict__ in,
                                               unsigned short* __restrict__ out, int n)
{
  int i = (blockIdx.x * 256 + threadIdx.x) * 4;
  if (i < n) {
    float4 f = *(const float4*)(in + i);
    union { int2 v; unsigned short u[4]; } o;
    o.u[0] = f2bf(f.x); o.u[1] = f2bf(f.y); o.u[2] = f2bf(f.z); o.u[3] = f2bf(f.w);
    *(int2*)(out + i) = o.v;
  }
}

// ---------------- mask int -> additive float bias (once per launch) ----------
__global__ __launch_bounds__(256) void mask2f(const int* __restrict__ m,
                                              float* __restrict__ o, int n)
{
  int i = blockIdx.x * 256 + threadIdx.x;
  if (i < n) o[i] = m[i] ? 0.0f : -1.0e9f;
}

// ---------------- LayerNorm: fp32 in -> bf16 out, one block per row of 1024 ----
// torch variant: unbiased std (ddof=1), eps added to std (not var)
__global__ __launch_bounds__(256) void ln_kernel(const float* __restrict__ in,
    const float* __restrict__ gam, const float* __restrict__ bet,
    unsigned short* __restrict__ out)
{
  const int row = blockIdx.x, t = threadIdx.x;
  const int base = t * 4;
  float4 raw = *(const float4*)(in + (size_t)row * D_MODEL + base);
  float v[4] = { raw.x, raw.y, raw.z, raw.w };
  float s  = v[0] + v[1] + v[2] + v[3];
  float s2 = v[0]*v[0] + v[1]*v[1] + v[2]*v[2] + v[3]*v[3];
  #pragma unroll
  for (int off = 32; off > 0; off >>= 1) {
    s  += __shfl_down(s,  off);
    s2 += __shfl_down(s2, off);
  }
  __shared__ float red[10];
  const int wid = t >> 6, lane = t & 63;
  if (lane == 0) { red[wid] = s; red[4 + wid] = s2; }
  __syncthreads();
  if (t == 0) {
    float ts  = red[0] + red[1] + red[2] + red[3];
    float ts2 = red[4] + red[5] + red[6] + red[7];
    float mean = ts * (1.0f / D_MODEL);
    float var  = (ts2 - (float)D_MODEL * mean * mean) * (1.0f / (D_MODEL - 1));
    var = fmaxf(var, 0.0f);
    red[8] = mean;
    red[9] = 1.0f / (sqrtf(var) + 1e-6f);
  }
  __syncthreads();
  const float mean = red[8], inv = red[9];
  float4 g4 = *(const float4*)(gam + base);
  float4 b4 = *(const float4*)(bet + base);
  union { int2 v; unsigned short u[4]; } o;
  o.u[0] = f2bf(g4.x * (v[0] - mean) * inv + b4.x);
  o.u[1] = f2bf(g4.y * (v[1] - mean) * inv + b4.y);
  o.u[2] = f2bf(g4.z * (v[2] - mean) * inv + b4.z);
  o.u[3] = f2bf(g4.w * (v[3] - mean) * inv + b4.w);
  *(int2*)(out + (size_t)row * D_MODEL + base) = o.v;
}

// ---------------- GEMM: C[m,n] = sum_k A[m,k] * Bw[n,k]  (+ epilogue) ----------
// All-bf16 operands; 2-phase pipeline: prefetch K-step t+1 via global_load_lds
// into the ALTERNATE static LDS buffer BEFORE computing step t (T3-minimum).
// Staging pointers hoisted. One __syncthreads per K-step.
// __launch_bounds__(256,4): VGPR<=128 -> 4 blocks/CU (R9: neutral, kept for
// stability). T1 XCD swizzle on the (x,y) block id.
// 128x128 tile, BK=32, 4 waves (2x2), each wave 64x64 via 4x4 mfma_16x16x32_bf16.
// QKV mode (outq!=null): N=3072 fused; col block 0->q, 1->k, 2->vt (transposed).
// Split-K mode (atomf!=null): grid.z = #splits, each handles K cols
//   [z*K, (z+1)*K); epilogue atomicAdd fp32 (bias by z==0 only).
//   Target must be pre-initialized (residual).
__global__ __launch_bounds__(256, 4) void gemm_bt(
    const unsigned short* __restrict__ A,   // [M,*] bf16, row stride sA
    const unsigned short* __restrict__ Bw,  // [N,*] bf16, row stride sB
    int K, int N, int sA, int sB,
    const float* __restrict__ bias,    // [N] fp32 or null
    int relu,
    const float* __restrict__ residf,  // [M,N] fp32 or null
    unsigned short* __restrict__ outb, // [M,N] bf16 or null
    float* __restrict__ outf,          // [M,N] fp32 or null
    float* __restrict__ atomf,         // [M,N] fp32 atomic-accum or null
    unsigned short* __restrict__ outq, // fused-QKV q  [M,1024] or null
    unsigned short* __restrict__ outk, //           k  [M,1024]
    unsigned short* __restrict__ outvt)//           v^T [(b,h),d,s]
{
  __shared__ __attribute__((aligned(16))) short sA0[128 * 32];
  __shared__ __attribute__((aligned(16))) short sA1[128 * 32];
  __shared__ __attribute__((aligned(16))) short sB0[128 * 32];
  __shared__ __attribute__((aligned(16))) short sB1[128 * 32];
  const int t = threadIdx.x;
  // T1: swizzle (x,y)-linearized block id (total always % 8 == 0 here)
  const int lid  = xcd_swz(blockIdx.y * gridDim.x + blockIdx.x,
                           gridDim.x * gridDim.y);
  const int tileN = (lid % gridDim.x) * 128;
  const int tileM = (lid / gridDim.x) * 128;
  const int kz = blockIdx.z;
  const size_t koff = (size_t)kz * K;
  const int wid = t >> 6, lane = t & 63;
  const int wM = (wid >> 1) * 64, wN = (wid & 1) * 64;
  const int quad = lane >> 4, lrow = lane & 15;

  f32x4 acc[4][4] = {};

  // hoisted staging pointers: thread t covers rows (t>>2) and (t>>2)+64, col (t&3)*8
  const unsigned short* pa = A  + (size_t)(tileM + (t >> 2)) * sA + koff + (t & 3) * 8;
  const unsigned short* pb = Bw + (size_t)(tileN + (t >> 2)) * sB + koff + (t & 3) * 8;
  const size_t a64 = (size_t)64 * sA, b64 = (size_t)64 * sB;

  auto stageTo = [&](short* dA, short* dB) {
    gl_lds16(pa,       dA + t * 8);
    gl_lds16(pa + a64, dA + (256 + t) * 8);
    gl_lds16(pb,       dB + t * 8);
    gl_lds16(pb + b64, dB + (256 + t) * 8);
    pa += 32; pb += 32;
  };
  auto compute = [&](const short* cA, const short* cB) {
    bf16x8 af[4], bfr[4];
    #pragma unroll
    for (int i = 0; i < 4; i++) {
      af[i]  = *(const bf16x8*)&cA[(wM + i * 16 + lrow) * 32 + quad * 8];
      bfr[i] = *(const bf16x8*)&cB[(wN + i * 16 + lrow) * 32 + quad * 8];
    }
    #pragma unroll
    for (int i = 0; i < 4; i++)
      #pragma unroll
      for (int j = 0; j < 4; j++)
        acc[i][j] = __builtin_amdgcn_mfma_f32_16x16x32_bf16(af[i], bfr[j], acc[i][j], 0, 0, 0);
  };

  const int nk = K >> 5;                 // always even for our shapes
  stageTo(sA0, sB0);
  __syncthreads();
  for (int ik = 0; ik < nk; ik += 2) {
    if (ik + 1 < nk) stageTo(sA1, sB1);
    compute(sA0, sB0);
    __syncthreads();
    if (ik + 2 < nk) stageTo(sA0, sB0);
    compute(sA1, sB1);
    __syncthreads();
  }

  // fused-QKV epilogue target for this block (tileN is 128-aligned; one cat/block)
  unsigned short* qk_out = nullptr;
  int qkv_cat = 0;
  if (outq) {
    qkv_cat = tileN >> 10;                 // 0=q 1=k 2=v
    qk_out = (qkv_cat == 0) ? outq : outk;
  }

  #pragma unroll
  for (int i = 0; i < 4; i++) {
    #pragma unroll
    for (int j = 0; j < 4; j++) {
      const int col  = tileN + wN + j * 16 + lrow;
      const int row0 = tileM + wM + i * 16 + quad * 4;
      const float bv = (bias && kz == 0) ? bias[col] : 0.0f;
      float vals[4];
      #pragma unroll
      for (int r = 0; r < 4; r++) {
        float val = acc[i][j][r] + bv;
        if (relu) val = fmaxf(val, 0.0f);
        if (residf) val += residf[(size_t)(row0 + r) * N + col];
        vals[r] = val;
      }
      if (outq) {
        const int lcol = col & 1023;
        if (qkv_cat < 2) {
          #pragma unroll
          for (int r = 0; r < 4; r++)
            qk_out[(size_t)(row0 + r) * D_MODEL + lcol] = f2bf(vals[r]);
        } else {
          // vt[((b*NH+h)*DK+d)*SEQ + s]: b=row>>11, s=row&2047, h=lcol>>6, d=lcol&63
          union { int2 v; unsigned short u[4]; } pk;
          #pragma unroll
          for (int r = 0; r < 4; r++) pk.u[r] = f2bf(vals[r]);
          size_t tidx = (((size_t)(row0 >> 11) * NH + (lcol >> 6)) * DK + (lcol & 63)) * SEQ + (row0 & 2047);
          *(int2*)(outvt + tidx) = pk.v;
        }
      } else if (atomf) {
        #pragma unroll
        for (int r = 0; r < 4; r++)
          atomicAdd(&atomf[(size_t)(row0 + r) * N + col], vals[r]);
      } else {
        #pragma unroll
        for (int r = 0; r < 4; r++) {
          const size_t idx = (size_t)(row0 + r) * N + col;
          if (outf) outf[idx] = vals[r];
          if (outb) outb[idx] = f2bf(vals[r]);
        }
      }
    }
  }
}

// ---------------- MFMA flash attention (v9: barrier-free, L2-direct K/V) ------
// R8 verified T1 made each (b,h)'s 1MB K/V panel XCD-local & L2-resident
// (FETCH 139->24.7MB). So LDS staging of K/V is pure overhead (m169 lesson:
// don't stage what L2-fits). This version:
//   - AQT=64, 4 waves, each wave owns 16 q-rows, fully independent.
//   - K/V/mask fragments read DIRECTLY from global as 16B vector loads
//     (L2-hit ~200cy, hidden by TLP + compiler cross-tile pipelining).
//   - Only Ps (8KB) in LDS, strictly WAVE-PRIVATE rows (wv*16..+15):
//     same-wave ds write->read is program-ordered -> ZERO __syncthreads.
//   - LDS 8.5KB, VGPR ~85 -> ~5 blocks/CU of grid's 8/CU; no drain stalls.
// Swapped QK^T, log2-domain softmax, defer-max, cvt_pk P pack, XOR-swizzled Ps.
// Og may alias Qg (Q frags register-resident before any write).
#define AQT 64
#define AKT 64
__global__ __launch_bounds__(256) void attn_mfma(
    const unsigned short* __restrict__ Qg,   // [B*S][D_MODEL] bf16
    const unsigned short* __restrict__ Kg,   // [B*S][D_MODEL] bf16
    const unsigned short* __restrict__ Vt,   // [(b*NH+h)*DK + d][SEQ] bf16 (transposed)
    const float* __restrict__ maddg,         // [B*S] precomputed additive bias
    unsigned short* __restrict__ Og)
{
  __shared__ __attribute__((aligned(16))) short Ps[64 * 64];

  // T1: swizzled logical id; q-tile fastest-varying -> each XCD owns 256
  // contiguous q-tiles = 8 whole (b,h) groups.
  const int bid = xcd_swz(blockIdx.x, gridDim.x);
  const int nqt = SEQ / AQT;          // 32
  const int b  = bid / (NH * nqt);
  const int h  = (bid / nqt) % NH;
  const int q0 = (bid % nqt) * AQT;
  const int t  = threadIdx.x;
  const int wv = t >> 6, lane = t & 63;
  const int quad = lane >> 4, l15 = lane & 15;
  const int sw = (l15 & 7) << 3;      // XOR swizzle for Ps
  const float SCL = 0.125f * 1.44269504f;   // score scale in log2 domain

  bf16x8 qf0, qf1;
  {
    const unsigned short* qrow =
        Qg + (size_t)(b * SEQ + q0 + wv * 16 + l15) * D_MODEL + h * DK;
    qf0 = *(const bf16x8*)(qrow + quad * 8);
    qf1 = *(const bf16x8*)(qrow + 32 + quad * 8);
  }
  f32x4 oacc[4] = {};
  float m_run = -1e30f, l_run = 0.0f;

  // direct-global fragment base pointers (all 16B aligned)
  const unsigned short* kfrag =
      Kg + (size_t)(b * SEQ + l15) * D_MODEL + h * DK + quad * 8;   // + (kt+ct*16)*D_MODEL
  const unsigned short* vfrag =
      Vt + ((size_t)(b * NH + h) * DK + l15) * SEQ + quad * 8;      // + dt*16*SEQ + kt
  const float* mg = maddg + b * SEQ + quad * 4;                     // + kt + ct*16
  const int prow = wv * 16 + l15;

  for (int kt = 0; kt < SEQ; kt += AKT) {
    // ---- QK^T (swapped): out[kv = ct*16+quad*4+r][q = l15], log2 domain ----
    f32x4 sc[4];
    #pragma unroll
    for (int ct = 0; ct < 4; ct++) {
      const unsigned short* kr = kfrag + (size_t)(kt + ct * 16) * D_MODEL;
      bf16x8 kb0 = *(const bf16x8*)(kr);
      bf16x8 kb1 = *(const bf16x8*)(kr + 32);
      f32x4 a = {};
      a = __builtin_amdgcn_mfma_f32_16x16x32_bf16(kb0, qf0, a, 0, 0, 0);
      a = __builtin_amdgcn_mfma_f32_16x16x32_bf16(kb1, qf1, a, 0, 0, 0);
      f32x4 md = *(const f32x4*)(mg + kt + ct * 16);
      #pragma unroll
      for (int r = 0; r < 4; r++) a[r] = a[r] * SCL + md[r];
      sc[ct] = a;
    }

    // ---- softmax: lane-local max over 16 kv, combine 4 quads ----
    float tmax = fmaxf(fmaxf(sc[0][0], sc[0][1]), fmaxf(sc[0][2], sc[0][3]));
    #pragma unroll
    for (int ct = 1; ct < 4; ct++)
      tmax = fmaxf(tmax, fmaxf(fmaxf(sc[ct][0], sc[ct][1]),
                               fmaxf(sc[ct][2], sc[ct][3])));
    tmax = fmaxf(tmax, __shfl_xor(tmax, 16));
    tmax = fmaxf(tmax, __shfl_xor(tmax, 32));

    // defer-max (T13): only rescale when max grew by > 8 nats (11.54 in log2)
    if (!__all(tmax - m_run <= 11.5415603f)) {
      float mn = fmaxf(m_run, tmax);
      float alpha = fexp2(m_run - mn);
      m_run = mn;
      l_run *= alpha;
      float a4[4];
      #pragma unroll
      for (int r = 0; r < 4; r++) a4[r] = __shfl(alpha, quad * 4 + r);
      #pragma unroll
      for (int dt = 0; dt < 4; dt++)
        #pragma unroll
        for (int r = 0; r < 4; r++) oacc[dt][r] *= a4[r];
    }

    // ---- P = 2^(S-m); packed bf16 -> wave-private Ps rows (no barrier) ----
    float rs = 0.0f;
    #pragma unroll
    for (int ct = 0; ct < 4; ct++) {
      float p0 = fexp2(sc[ct][0] - m_run);
      float p1 = fexp2(sc[ct][1] - m_run);
      float p2 = fexp2(sc[ct][2] - m_run);
      float p3 = fexp2(sc[ct][3] - m_run);
      rs += (p0 + p1) + (p2 + p3);
      unsigned int lo, hi;
      asm("v_cvt_pk_bf16_f32 %0, %1, %2" : "=v"(lo) : "v"(p0), "v"(p1));
      asm("v_cvt_pk_bf16_f32 %0, %1, %2" : "=v"(hi) : "v"(p2), "v"(p3));
      int2 pv; pv.x = (int)lo; pv.y = (int)hi;
      *(int2*)&Ps[prow * 64 + ((ct * 16 + quad * 4) ^ sw)] = pv;
    }
    rs += __shfl_xor(rs, 16);
    rs += __shfl_xor(rs, 32);
    l_run += rs;

    // ---- PV: A = P rows (own wave), B = V fragments direct from global ----
    bf16x8 pf0 = *(const bf16x8*)&Ps[prow * 64 + ((quad * 8) ^ sw)];
    bf16x8 pf1 = *(const bf16x8*)&Ps[prow * 64 + ((32 + quad * 8) ^ sw)];
    #pragma unroll
    for (int dt = 0; dt < 4; dt++) {
      const unsigned short* vr = vfrag + (size_t)(dt * 16) * SEQ + kt;
      bf16x8 vb0 = *(const bf16x8*)(vr);
      bf16x8 vb1 = *(const bf16x8*)(vr + 32);
      oacc[dt] = __builtin_amdgcn_mfma_f32_16x16x32_bf16(pf0, vb0, oacc[dt], 0, 0, 0);
      oacc[dt] = __builtin_amdgcn_mfma_f32_16x16x32_bf16(pf1, vb1, oacc[dt], 0, 0, 0);
    }
  }

  // transport 1/l from lane-layout (q=l15) to C-layout (q=quad*4+r)
  float li = 1.0f / l_run;
  float linv4[4];
  #pragma unroll
  for (int r = 0; r < 4; r++) linv4[r] = __shfl(li, quad * 4 + r);
  #pragma unroll
  for (int dt = 0; dt < 4; dt++)
    #pragma unroll
    for (int r = 0; r < 4; r++)
      Og[(size_t)(b * SEQ + q0 + wv * 16 + quad * 4 + r) * D_MODEL + h * DK + dt * 16 + l15] =
        f2bf(oacc[dt][r] * linv4[r]);
}

// ---------------- launch ----------------
// fp32 I/O. All GEMMs bf16 with just-in-time weight conversion. NO ws_size gate.
// ws high-water 48MB + 32KB:
//   phase A: q [0,16)  k [16,32)  vt [32,48)  maddg [48MB, +32KB)
//   phase B (after attn): ao=q, wo16 -> [16,18) (k dead)
//   phase C (after o-proj): w1 -> [0,8), w2 -> [8,16) (ao dead); ln2 -> [32,48)
//            hff chunk -> [16,32)
// d_out as scratch: ln1b [0,16MB), wqkv16 [16,22MB); o-proj overwrites all with x1 fp32.
extern "C" void kernel_launch(void* const* d_in, const int* in_sizes, int n_in,
                              void* d_out, int out_size, void* d_ws, size_t ws_size,
                              hipStream_t stream)
{
  (void)in_sizes; (void)n_in; (void)out_size; (void)ws_size;
  const float* x   = (const float*)d_in[0];
  const int*   msk = (const int*)d_in[1];
  const float* w_q = (const float*)d_in[2];
  const float* w_k = (const float*)d_in[3];
  const float* w_v = (const float*)d_in[4];
  const float* w_o = (const float*)d_in[5];
  const float* w1  = (const float*)d_in[6];
  const float* b1  = (const float*)d_in[7];
  const float* w2  = (const float*)d_in[8];
  const float* b2  = (const float*)d_in[9];
  const float* g1  = (const float*)d_in[10];
  const float* be1 = (const float*)d_in[11];
  const float* g2  = (const float*)d_in[12];
  const float* be2 = (const float*)d_in[13];
  float* outf = (float*)d_out;

  char* ws = (char*)d_ws;
  const size_t MB = 1024 * 1024;
  unsigned short* q_b  = (unsigned short*)(ws + 0);        // 16MB -> ao
  unsigned short* k_b  = (unsigned short*)(ws + 16 * MB);  // 16MB -> wo16 -> hff chunk
  unsigned short* vt_b = (unsigned short*)(ws + 32 * MB);  // 16MB -> ln2b
  unsigned short* wo16 = (unsigned short*)(ws + 16 * MB);  // 2MB (k dead after attn)
  unsigned short* w116 = (unsigned short*)(ws + 0);        // 8MB (ao dead after o-proj)
  unsigned short* w216 = (unsigned short*)(ws + 8 * MB);   // 8MB
  unsigned short* ln2b = vt_b;                             // 16MB (vt dead after attn)
  unsigned short* hffc = k_b;                              // 16MB chunk
  float* maddg = (float*)(ws + 48 * MB);                   // 32KB mask bias

  unsigned short* ln1b   = (unsigned short*)d_out;                  // [0,16MB) of d_out
  unsigned short* wqkv16 = (unsigned short*)d_out + 8 * 1024 * 1024;// [16,22MB) of d_out

  dim3 blk(256);
  const int nw = D_MODEL * D_MODEL;  // 1M elems
  const int nf = DFF * D_MODEL;      // 4M elems

  // phase A: weights q|k|v -> fused bf16 [3072,1024] in d_out scratch; LN1; mask
  cvt_f2b<<<nw / 1024, blk, 0, stream>>>(w_q, wqkv16, nw);
  cvt_f2b<<<nw / 1024, blk, 0, stream>>>(w_k, wqkv16 + nw, nw);
  cvt_f2b<<<nw / 1024, blk, 0, stream>>>(w_v, wqkv16 + 2 * nw, nw);
  mask2f<<<NROWS / 256, blk, 0, stream>>>(msk, maddg, NROWS);
  ln_kernel<<<NROWS, blk, 0, stream>>>(x, g1, be1, ln1b);

  // fused QKV: [8192,1024] x [3072,1024]^T -> q, k, vt  (1536 blocks, %8==0)
  dim3 gqkv(3 * D_MODEL / 128, NROWS / 128);  // (24, 64)
  gemm_bt<<<gqkv, blk, 0, stream>>>(ln1b, wqkv16, D_MODEL, 3 * D_MODEL, D_MODEL, D_MODEL,
                                    nullptr, 0, nullptr, nullptr, nullptr, nullptr,
                                    q_b, k_b, vt_b);

  // attention (output in-place over q); AQT=64 -> 2048 blocks (%8==0)
  attn_mfma<<<BATCH * NH * (SEQ / AQT), blk, 0, stream>>>(q_b, k_b, vt_b, maddg, q_b);

  // phase B: wo -> dead k region; o-proj + residual(x) -> x1 = d_out (fp32)
  cvt_f2b<<<nw / 1024, blk, 0, stream>>>(w_o, wo16, nw);
  dim3 gN1024(D_MODEL / 128, NROWS / 128);  // (8, 64) = 512 blocks
  gemm_bt<<<gN1024, blk, 0, stream>>>(q_b, wo16, D_MODEL, D_MODEL, D_MODEL, D_MODEL,
                                      nullptr, 0, x, nullptr, outf, nullptr,
                                      nullptr, nullptr, nullptr);

  // phase C: w1/w2 -> dead ao region; LN2 -> dead vt region; chunked FFN
  cvt_f2b<<<nf / 1024, blk, 0, stream>>>(w1, w116, nf);
  cvt_f2b<<<nf / 1024, blk, 0, stream>>>(w2, w216, nf);
  ln_kernel<<<NROWS, blk, 0, stream>>>(outf, g2, be2, ln2b);
  for (int c = 0; c < NCHUNK; c++) {
    const size_t ro = (size_t)c * CHUNK;
    dim3 g1c(DFF / 128,     CHUNK / 128);      // (32, 16) = 512 blocks
    dim3 g2c(D_MODEL / 128, CHUNK / 128, 4);   // (8, 16, 4): xy=128 blocks, split-K
    gemm_bt<<<g1c, blk, 0, stream>>>(ln2b + ro * D_MODEL, w116, D_MODEL, DFF,
                                     D_MODEL, D_MODEL, b1, 1,
                                     nullptr, hffc, nullptr, nullptr,
                                     nullptr, nullptr, nullptr);
    // FFN2 split-K=4 (K=1024 each): outf already holds x1 (residual) in place;
    // partials accumulate via device-scope fp32 atomics, bias from split 0.
    gemm_bt<<<g2c, blk, 0, stream>>>(hffc, w216, DFF / 4, D_MODEL, DFF, DFF, b2, 0,
                                     nullptr, nullptr, nullptr, outf + ro * D_MODEL,
                                     nullptr, nullptr, nullptr);
  }
}

// Round 11
// 693.118 us; speedup vs baseline: 1.5058x; 1.5058x over previous
//
#include <hip/hip_runtime.h>

#define D_MODEL 1024
#define NH 16
#define DK 64
#define DFF 4096
#define SEQ 2048
#define BATCH 4
#define NROWS (BATCH*SEQ)   // 8192
#define CHUNK 2048          // FFN row-chunk (16MB bf16 hidden fits dead k region)
#define NCHUNK (NROWS/CHUNK)

typedef short bf16x8 __attribute__((ext_vector_type(8)));
typedef float f32x4 __attribute__((ext_vector_type(4)));

__device__ __forceinline__ float bf2f(unsigned short u){
  union { float f; unsigned int i; } x; x.i = ((unsigned int)u) << 16; return x.f;
}
__device__ __forceinline__ unsigned short f2bf(float f){
  union { float f; unsigned int i; } x; x.f = f;
  unsigned int r = x.i + 0x7fffu + ((x.i >> 16) & 1u);
  return (unsigned short)(r >> 16);
}
__device__ __forceinline__ float fexp2(float x){
#if __has_builtin(__builtin_amdgcn_exp2f)
  return __builtin_amdgcn_exp2f(x);
#else
  return __exp2f(x);
#endif
}

// async global->LDS, 16B per lane (m97 pattern; LDS dest = wave base + lane*16)
__device__ __forceinline__ void gl_lds16(const void* g, void* l) {
  __builtin_amdgcn_global_load_lds((const __attribute__((address_space(1))) void*)g,
                                   (__attribute__((address_space(3))) void*)l, 16, 0, 0);
}

// T1 XCD-aware swizzle: hardware block hid lands on XCD hid%8; remap so each
// XCD gets a CONTIGUOUS logical chunk -> blocks sharing operand panels hit the
// same per-XCD L2. Bijective iff total % 8 == 0 (true at every call site).
// [R8 verified: attn FETCH_SIZE 139MB -> 24.7MB]
__device__ __forceinline__ int xcd_swz(int hid, int total) {
  return (hid & 7) * (total >> 3) + (hid >> 3);
}

// ---------------- fp32 -> bf16 bulk convert (weights) ----------------
__global__ __launch_bounds__(256) void cvt_f2b(const float* __restrict__ in,
                                               unsigned short* __restrict__ out, int n)
{
  int i = (blockIdx.x * 256 + threadIdx.x) * 4;
  if (i < n) {
    float4 f = *(const float4*)(in + i);
    union { int2 v; unsigned short u[4]; } o;
    o.u[0] = f2bf(f.x); o.u[1] = f2bf(f.y); o.u[2] = f2bf(f.z); o.u[3] = f2bf(f.w);
    *(int2*)(out + i) = o.v;
  }
}

// ---------------- LayerNorm: fp32 in -> bf16 out, one block per row of 1024 ----
// torch variant: unbiased std (ddof=1), eps added to std (not var)
__global__ __launch_bounds__(256) void ln_kernel(const float* __restrict__ in,
    const float* __restrict__ gam, const float* __restrict__ bet,
    unsigned short* __restrict__ out)
{
  const int row = blockIdx.x, t = threadIdx.x;
  const int base = t * 4;
  float4 raw = *(const float4*)(in + (size_t)row * D_MODEL + base);
  float v[4] = { raw.x, raw.y, raw.z, raw.w };
  float s  = v[0] + v[1] + v[2] + v[3];
  float s2 = v[0]*v[0] + v[1]*v[1] + v[2]*v[2] + v[3]*v[3];
  #pragma unroll
  for (int off = 32; off > 0; off >>= 1) {
    s  += __shfl_down(s,  off);
    s2 += __shfl_down(s2, off);
  }
  __shared__ float red[10];
  const int wid = t >> 6, lane = t & 63;
  if (lane == 0) { red[wid] = s; red[4 + wid] = s2; }
  __syncthreads();
  if (t == 0) {
    float ts  = red[0] + red[1] + red[2] + red[3];
    float ts2 = red[4] + red[5] + red[6] + red[7];
    float mean = ts * (1.0f / D_MODEL);
    float var  = (ts2 - (float)D_MODEL * mean * mean) * (1.0f / (D_MODEL - 1));
    var = fmaxf(var, 0.0f);
    red[8] = mean;
    red[9] = 1.0f / (sqrtf(var) + 1e-6f);
  }
  __syncthreads();
  const float mean = red[8], inv = red[9];
  float4 g4 = *(const float4*)(gam + base);
  float4 b4 = *(const float4*)(bet + base);
  union { int2 v; unsigned short u[4]; } o;
  o.u[0] = f2bf(g4.x * (v[0] - mean) * inv + b4.x);
  o.u[1] = f2bf(g4.y * (v[1] - mean) * inv + b4.y);
  o.u[2] = f2bf(g4.z * (v[2] - mean) * inv + b4.z);
  o.u[3] = f2bf(g4.w * (v[3] - mean) * inv + b4.w);
  *(int2*)(out + (size_t)row * D_MODEL + base) = o.v;
}

// ---------------- GEMM: C[m,n] = sum_k A[m,k] * Bw[n,k]  (+ epilogue) ----------
// All-bf16 operands; 2-phase pipeline: prefetch K-step t+1 via global_load_lds
// into the ALTERNATE static LDS buffer BEFORE computing step t (T3-minimum).
// Staging pointers hoisted. One __syncthreads per K-step.
// NEW (R10): LDS slot swizzle. [128][32]-short rows are 64B = 4x16B slots;
// naive fragment reads (16 lanes, row-stride 64B, fixed slot) are an 8-way
// bank conflict. Staged with pre-swizzled GLOBAL source slot^((row>>1)&3)
// (LDS dest stays linear, m173 pattern) and read back with the same XOR,
// which is per-lane constant: quad ^ ((lrow>>1)&3). -> 2-way (free, m136).
// __launch_bounds__(256,4) + T1 XCD swizzle on (x,y) block id.
// 128x128 tile, BK=32, 4 waves (2x2), each wave 64x64 via 4x4 mfma_16x16x32_bf16.
// QKV mode (outq!=null): N=3072 fused; col block 0->q, 1->k, 2->vt (transposed).
// Split-K mode (atomf!=null): grid.z = #splits, each handles K cols
//   [z*K, (z+1)*K); epilogue atomicAdd fp32 (bias by z==0 only).
//   Target must be pre-initialized (residual).
__global__ __launch_bounds__(256, 4) void gemm_bt(
    const unsigned short* __restrict__ A,   // [M,*] bf16, row stride sA
    const unsigned short* __restrict__ Bw,  // [N,*] bf16, row stride sB
    int K, int N, int sA, int sB,
    const float* __restrict__ bias,    // [N] fp32 or null
    int relu,
    const float* __restrict__ residf,  // [M,N] fp32 or null
    unsigned short* __restrict__ outb, // [M,N] bf16 or null
    float* __restrict__ outf,          // [M,N] fp32 or null
    float* __restrict__ atomf,         // [M,N] fp32 atomic-accum or null
    unsigned short* __restrict__ outq, // fused-QKV q  [M,1024] or null
    unsigned short* __restrict__ outk, //           k  [M,1024]
    unsigned short* __restrict__ outvt)//           v^T [(b,h),d,s]
{
  __shared__ __attribute__((aligned(16))) short sA0[128 * 32];
  __shared__ __attribute__((aligned(16))) short sA1[128 * 32];
  __shared__ __attribute__((aligned(16))) short sB0[128 * 32];
  __shared__ __attribute__((aligned(16))) short sB1[128 * 32];
  const int t = threadIdx.x;
  // T1: swizzle (x,y)-linearized block id (total always % 8 == 0 here)
  const int lid  = xcd_swz(blockIdx.y * gridDim.x + blockIdx.x,
                           gridDim.x * gridDim.y);
  const int tileN = (lid % gridDim.x) * 128;
  const int tileM = (lid / gridDim.x) * 128;
  const int kz = blockIdx.z;
  const size_t koff = (size_t)kz * K;
  const int wid = t >> 6, lane = t & 63;
  const int wM = (wid >> 1) * 64, wN = (wid & 1) * 64;
  const int quad = lane >> 4, lrow = lane & 15;

  f32x4 acc[4][4] = {};

  // hoisted staging pointers: thread t covers rows (t>>2) and (t>>2)+64.
  // Global col slot is PRE-SWIZZLED: (t&3) ^ ((t>>3)&3); rows r and r+64 share
  // the same swizzle key ((r>>1)&3, 64 = 0 mod 4 after >>1... 32 ≡ 0 mod 4).
  const int slotg = ((t & 3) ^ ((t >> 3) & 3)) * 8;
  const unsigned short* pa = A  + (size_t)(tileM + (t >> 2)) * sA + koff + slotg;
  const unsigned short* pb = Bw + (size_t)(tileN + (t >> 2)) * sB + koff + slotg;
  const size_t a64 = (size_t)64 * sA, b64 = (size_t)64 * sB;

  auto stageTo = [&](short* dA, short* dB) {
    gl_lds16(pa,       dA + t * 8);
    gl_lds16(pa + a64, dA + (256 + t) * 8);
    gl_lds16(pb,       dB + t * 8);
    gl_lds16(pb + b64, dB + (256 + t) * 8);
    pa += 32; pb += 32;
  };
  // read-side swizzle: per-lane constant slot XOR (see header comment)
  const int sq = (quad ^ ((lrow >> 1) & 3)) * 8;
  auto compute = [&](const short* cA, const short* cB) {
    bf16x8 af[4], bfr[4];
    #pragma unroll
    for (int i = 0; i < 4; i++) {
      af[i]  = *(const bf16x8*)&cA[(wM + i * 16 + lrow) * 32 + sq];
      bfr[i] = *(const bf16x8*)&cB[(wN + i * 16 + lrow) * 32 + sq];
    }
    #pragma unroll
    for (int i = 0; i < 4; i++)
      #pragma unroll
      for (int j = 0; j < 4; j++)
        acc[i][j] = __builtin_amdgcn_mfma_f32_16x16x32_bf16(af[i], bfr[j], acc[i][j], 0, 0, 0);
  };

  const int nk = K >> 5;                 // always even for our shapes
  stageTo(sA0, sB0);
  __syncthreads();
  for (int ik = 0; ik < nk; ik += 2) {
    if (ik + 1 < nk) stageTo(sA1, sB1);
    compute(sA0, sB0);
    __syncthreads();
    if (ik + 2 < nk) stageTo(sA0, sB0);
    compute(sA1, sB1);
    __syncthreads();
  }

  // fused-QKV epilogue target for this block (tileN is 128-aligned; one cat/block)
  unsigned short* qk_out = nullptr;
  int qkv_cat = 0;
  if (outq) {
    qkv_cat = tileN >> 10;                 // 0=q 1=k 2=v
    qk_out = (qkv_cat == 0) ? outq : outk;
  }

  #pragma unroll
  for (int i = 0; i < 4; i++) {
    #pragma unroll
    for (int j = 0; j < 4; j++) {
      const int col  = tileN + wN + j * 16 + lrow;
      const int row0 = tileM + wM + i * 16 + quad * 4;
      const float bv = (bias && kz == 0) ? bias[col] : 0.0f;
      float vals[4];
      #pragma unroll
      for (int r = 0; r < 4; r++) {
        float val = acc[i][j][r] + bv;
        if (relu) val = fmaxf(val, 0.0f);
        if (residf) val += residf[(size_t)(row0 + r) * N + col];
        vals[r] = val;
      }
      if (outq) {
        const int lcol = col & 1023;
        if (qkv_cat < 2) {
          #pragma unroll
          for (int r = 0; r < 4; r++)
            qk_out[(size_t)(row0 + r) * D_MODEL + lcol] = f2bf(vals[r]);
        } else {
          // vt[((b*NH+h)*DK+d)*SEQ + s]: b=row>>11, s=row&2047, h=lcol>>6, d=lcol&63
          union { int2 v; unsigned short u[4]; } pk;
          #pragma unroll
          for (int r = 0; r < 4; r++) pk.u[r] = f2bf(vals[r]);
          size_t tidx = (((size_t)(row0 >> 11) * NH + (lcol >> 6)) * DK + (lcol & 63)) * SEQ + (row0 & 2047);
          *(int2*)(outvt + tidx) = pk.v;
        }
      } else if (atomf) {
        #pragma unroll
        for (int r = 0; r < 4; r++)
          atomicAdd(&atomf[(size_t)(row0 + r) * N + col], vals[r]);
      } else {
        #pragma unroll
        for (int r = 0; r < 4; r++) {
          const size_t idx = (size_t)(row0 + r) * N + col;
          if (outf) outf[idx] = vals[r];
          if (outb) outb[idx] = f2bf(vals[r]);
        }
      }
    }
  }
}

// ---------------- MFMA flash attention (v7 REVERT: R8-measured-best 142.5us) --
// R10's barrier-free L2-direct variant was 3.4x WORSE (512us): 16-lane x 2KB
// strided gathers destroyed coalescing; MfmaUtil 5.5%. LDS staging restored.
// Block = 4 waves, 128 Q-rows of one (b,h); each wave owns 2 groups of 16 q.
// T1 XCD swizzle (FETCH 139->24.7MB verified). Per tile, phase-split (T15):
// QK both groups w/ shared K frags; softmax to Ps0/Ps1; PV both groups w/
// shared V frags. Swapped QK^T, log2-domain softmax, defer-max; LDS [64][64]
// XOR-swizzled; gl_lds16 with pre-swizzled source. Mask staged from int*.
// Og may alias Qg (both groups' Q frags register-resident before any write).
#define AQT 128
#define AKT 64
__global__ __launch_bounds__(256) void attn_mfma(
    const unsigned short* __restrict__ Qg,   // [B*S][D_MODEL] bf16
    const unsigned short* __restrict__ Kg,   // [B*S][D_MODEL] bf16
    const unsigned short* __restrict__ Vt,   // [(b*NH+h)*DK + d][SEQ] bf16 (transposed)
    const int* __restrict__ mask,            // [B*S]
    unsigned short* __restrict__ Og)
{
  __shared__ __attribute__((aligned(16))) short Ks[AKT * 64];
  __shared__ __attribute__((aligned(16))) short Vs[DK * 64];
  __shared__ __attribute__((aligned(16))) short Ps0[64 * 64];
  __shared__ __attribute__((aligned(16))) short Ps1[64 * 64];
  __shared__ __attribute__((aligned(16))) float maddf[AKT];

  // T1: swizzled logical id; q-tile fastest-varying -> each XCD owns whole
  // (b,h) groups (1024/8 = 128 = 8 groups).
  const int bid = xcd_swz(blockIdx.x, gridDim.x);
  const int nqt = SEQ / AQT;          // 16
  const int b  = bid / (NH * nqt);
  const int h  = (bid / nqt) % NH;
  const int q0 = (bid % nqt) * AQT;
  const int t  = threadIdx.x;
  const int wv = t >> 6, lane = t & 63;
  const int quad = lane >> 4, l15 = lane & 15;
  const int sw = (l15 & 7) << 3;      // shared XOR swizzle for all row&7==l15&7 reads
  const float SCL = 0.125f * 1.44269504f;   // score scale in log2 domain

  bf16x8 qf[2][2];
  #pragma unroll
  for (int g = 0; g < 2; g++) {
    const unsigned short* qrow =
        Qg + (size_t)(b * SEQ + q0 + g * 64 + wv * 16 + l15) * D_MODEL + h * DK;
    qf[g][0] = *(const bf16x8*)(qrow + quad * 8);
    qf[g][1] = *(const bf16x8*)(qrow + 32 + quad * 8);
  }
  f32x4 oacc[2][4] = {};
  float m_run[2] = { -1e30f, -1e30f };
  float l_run[2] = { 0.0f, 0.0f };

  // hoisted staging pointers: thread t covers rows (t>>3) and (t>>3)+32,
  // byte-col ((t&7)*8)^swizzle — same swizzle both halves ((row+32)&7 == row&7).
  const int srow = t >> 3;
  const int scol = ((t & 7) * 8) ^ ((srow & 7) << 3);
  const unsigned short* kp = Kg + (size_t)(b * SEQ + srow) * D_MODEL + h * DK + scol;
  const unsigned short* vp = Vt + ((size_t)(b * NH + h) * DK + srow) * SEQ + scol;
  const int* mp = mask + b * SEQ;
  const int prow = wv * 16 + l15;

  for (int kt = 0; kt < SEQ; kt += AKT) {
    gl_lds16(kp,                  &Ks[t * 8]);
    gl_lds16(kp + 32 * D_MODEL,   &Ks[(256 + t) * 8]);
    gl_lds16(vp,                  &Vs[t * 8]);
    gl_lds16(vp + 32 * SEQ,       &Vs[(256 + t) * 8]);
    if (t < AKT) maddf[t] = mp[t] ? 0.0f : -1.0e9f;
    __syncthreads();

    // ---- P1: QK^T both groups, shared K frags; scores in log2 domain ----
    f32x4 sc[2][4];
    #pragma unroll
    for (int ct = 0; ct < 4; ct++) {
      const int krow = ct * 16 + l15;
      bf16x8 kb0 = *(const bf16x8*)&Ks[krow * 64 + ((quad * 8) ^ sw)];
      bf16x8 kb1 = *(const bf16x8*)&Ks[krow * 64 + ((32 + quad * 8) ^ sw)];
      f32x4 a0 = {}, a1 = {};
      a0 = __builtin_amdgcn_mfma_f32_16x16x32_bf16(kb0, qf[0][0], a0, 0, 0, 0);
      a0 = __builtin_amdgcn_mfma_f32_16x16x32_bf16(kb1, qf[0][1], a0, 0, 0, 0);
      a1 = __builtin_amdgcn_mfma_f32_16x16x32_bf16(kb0, qf[1][0], a1, 0, 0, 0);
      a1 = __builtin_amdgcn_mfma_f32_16x16x32_bf16(kb1, qf[1][1], a1, 0, 0, 0);
      f32x4 md = *(const f32x4*)&maddf[ct * 16 + quad * 4];
      #pragma unroll
      for (int r = 0; r < 4; r++) {
        a0[r] = a0[r] * SCL + md[r];
        a1[r] = a1[r] * SCL + md[r];
      }
      sc[0][ct] = a0; sc[1][ct] = a1;
    }

    // ---- P2: softmax per group into its OWN P buffer ----
    #pragma unroll
    for (int g = 0; g < 2; g++) {
      short* Pg = g ? Ps1 : Ps0;
      float tmax = fmaxf(fmaxf(sc[g][0][0], sc[g][0][1]), fmaxf(sc[g][0][2], sc[g][0][3]));
      #pragma unroll
      for (int ct = 1; ct < 4; ct++)
        tmax = fmaxf(tmax, fmaxf(fmaxf(sc[g][ct][0], sc[g][ct][1]),
                                 fmaxf(sc[g][ct][2], sc[g][ct][3])));
      tmax = fmaxf(tmax, __shfl_xor(tmax, 16));
      tmax = fmaxf(tmax, __shfl_xor(tmax, 32));

      // defer-max (T13): only rescale when max grew by > 8 nats (11.54 in log2)
      if (!__all(tmax - m_run[g] <= 11.5415603f)) {
        float mn = fmaxf(m_run[g], tmax);
        float alpha = fexp2(m_run[g] - mn);
        m_run[g] = mn;
        l_run[g] *= alpha;
        float a4[4];
        #pragma unroll
        for (int r = 0; r < 4; r++) a4[r] = __shfl(alpha, quad * 4 + r);
        #pragma unroll
        for (int dt = 0; dt < 4; dt++)
          #pragma unroll
          for (int r = 0; r < 4; r++) oacc[g][dt][r] *= a4[r];
      }

      // P = 2^(S - m); packed bf16 store: 4x ds_write_b64 (P[q][kv], swizzled)
      float rs = 0.0f;
      #pragma unroll
      for (int ct = 0; ct < 4; ct++) {
        float p0 = fexp2(sc[g][ct][0] - m_run[g]);
        float p1 = fexp2(sc[g][ct][1] - m_run[g]);
        float p2 = fexp2(sc[g][ct][2] - m_run[g]);
        float p3 = fexp2(sc[g][ct][3] - m_run[g]);
        rs += (p0 + p1) + (p2 + p3);
        unsigned int lo, hi;
        asm("v_cvt_pk_bf16_f32 %0, %1, %2" : "=v"(lo) : "v"(p0), "v"(p1));
        asm("v_cvt_pk_bf16_f32 %0, %1, %2" : "=v"(hi) : "v"(p2), "v"(p3));
        int2 pv; pv.x = (int)lo; pv.y = (int)hi;
        *(int2*)&Pg[prow * 64 + ((ct * 16 + quad * 4) ^ sw)] = pv;
      }
      rs += __shfl_xor(rs, 16);
      rs += __shfl_xor(rs, 32);
      l_run[g] += rs;
    }

    // ---- P3: PV both groups, shared V frags ----
    bf16x8 pf00 = *(const bf16x8*)&Ps0[prow * 64 + ((quad * 8) ^ sw)];
    bf16x8 pf01 = *(const bf16x8*)&Ps0[prow * 64 + ((32 + quad * 8) ^ sw)];
    bf16x8 pf10 = *(const bf16x8*)&Ps1[prow * 64 + ((quad * 8) ^ sw)];
    bf16x8 pf11 = *(const bf16x8*)&Ps1[prow * 64 + ((32 + quad * 8) ^ sw)];
    #pragma unroll
    for (int dt = 0; dt < 4; dt++) {
      const int vrow = dt * 16 + l15;
      bf16x8 vb0 = *(const bf16x8*)&Vs[vrow * 64 + ((quad * 8) ^ sw)];
      bf16x8 vb1 = *(const bf16x8*)&Vs[vrow * 64 + ((32 + quad * 8) ^ sw)];
      oacc[0][dt] = __builtin_amdgcn_mfma_f32_16x16x32_bf16(pf00, vb0, oacc[0][dt], 0, 0, 0);
      oacc[0][dt] = __builtin_amdgcn_mfma_f32_16x16x32_bf16(pf01, vb1, oacc[0][dt], 0, 0, 0);
      oacc[1][dt] = __builtin_amdgcn_mfma_f32_16x16x32_bf16(pf10, vb0, oacc[1][dt], 0, 0, 0);
      oacc[1][dt] = __builtin_amdgcn_mfma_f32_16x16x32_bf16(pf11, vb1, oacc[1][dt], 0, 0, 0);
    }
    __syncthreads();
    kp += (size_t)AKT * D_MODEL; vp += AKT; mp += AKT;
  }

  // transport 1/l from lane-layout (q=l15) to C-layout (q=quad*4+r)
  #pragma unroll
  for (int g = 0; g < 2; g++) {
    float li = 1.0f / l_run[g];
    float linv4[4];
    #pragma unroll
    for (int r = 0; r < 4; r++) linv4[r] = __shfl(li, quad * 4 + r);
    #pragma unroll
    for (int dt = 0; dt < 4; dt++)
      #pragma unroll
      for (int r = 0; r < 4; r++)
        Og[(size_t)(b * SEQ + q0 + g * 64 + wv * 16 + quad * 4 + r) * D_MODEL + h * DK + dt * 16 + l15] =
          f2bf(oacc[g][dt][r] * linv4[r]);
  }
}

// ---------------- launch ----------------
// fp32 I/O. All GEMMs bf16 with just-in-time weight conversion. NO ws_size gate.
// ws high-water 48MB:
//   phase A: q [0,16)  k [16,32)  vt [32,48)
//   phase B (after attn): ao=q, wo16 -> [16,18) (k dead)
//   phase C (after o-proj): w1 -> [0,8), w2 -> [8,16) (ao dead); ln2 -> [32,48)
//            hff chunk -> [16,32)
// d_out as scratch: ln1b [0,16MB), wqkv16 [16,22MB); o-proj overwrites all with x1 fp32.
extern "C" void kernel_launch(void* const* d_in, const int* in_sizes, int n_in,
                              void* d_out, int out_size, void* d_ws, size_t ws_size,
                              hipStream_t stream)
{
  (void)in_sizes; (void)n_in; (void)out_size; (void)ws_size;
  const float* x   = (const float*)d_in[0];
  const int*   msk = (const int*)d_in[1];
  const float* w_q = (const float*)d_in[2];
  const float* w_k = (const float*)d_in[3];
  const float* w_v = (const float*)d_in[4];
  const float* w_o = (const float*)d_in[5];
  const float* w1  = (const float*)d_in[6];
  const float* b1  = (const float*)d_in[7];
  const float* w2  = (const float*)d_in[8];
  const float* b2  = (const float*)d_in[9];
  const float* g1  = (const float*)d_in[10];
  const float* be1 = (const float*)d_in[11];
  const float* g2  = (const float*)d_in[12];
  const float* be2 = (const float*)d_in[13];
  float* outf = (float*)d_out;

  char* ws = (char*)d_ws;
  const size_t MB = 1024 * 1024;
  unsigned short* q_b  = (unsigned short*)(ws + 0);        // 16MB -> ao
  unsigned short* k_b  = (unsigned short*)(ws + 16 * MB);  // 16MB -> wo16 -> hff chunk
  unsigned short* vt_b = (unsigned short*)(ws + 32 * MB);  // 16MB -> ln2b
  unsigned short* wo16 = (unsigned short*)(ws + 16 * MB);  // 2MB (k dead after attn)
  unsigned short* w116 = (unsigned short*)(ws + 0);        // 8MB (ao dead after o-proj)
  unsigned short* w216 = (unsigned short*)(ws + 8 * MB);   // 8MB
  unsigned short* ln2b = vt_b;                             // 16MB (vt dead after attn)
  unsigned short* hffc = k_b;                              // 16MB chunk

  unsigned short* ln1b   = (unsigned short*)d_out;                  // [0,16MB) of d_out
  unsigned short* wqkv16 = (unsigned short*)d_out + 8 * 1024 * 1024;// [16,22MB) of d_out

  dim3 blk(256);
  const int nw = D_MODEL * D_MODEL;  // 1M elems
  const int nf = DFF * D_MODEL;      // 4M elems

  // phase A: weights q|k|v -> fused bf16 [3072,1024] in d_out scratch; LN1
  cvt_f2b<<<nw / 1024, blk, 0, stream>>>(w_q, wqkv16, nw);
  cvt_f2b<<<nw / 1024, blk, 0, stream>>>(w_k, wqkv16 + nw, nw);
  cvt_f2b<<<nw / 1024, blk, 0, stream>>>(w_v, wqkv16 + 2 * nw, nw);
  ln_kernel<<<NROWS, blk, 0, stream>>>(x, g1, be1, ln1b);

  // fused QKV: [8192,1024] x [3072,1024]^T -> q, k, vt  (1536 blocks, %8==0)
  dim3 gqkv(3 * D_MODEL / 128, NROWS / 128);  // (24, 64)
  gemm_bt<<<gqkv, blk, 0, stream>>>(ln1b, wqkv16, D_MODEL, 3 * D_MODEL, D_MODEL, D_MODEL,
                                    nullptr, 0, nullptr, nullptr, nullptr, nullptr,
                                    q_b, k_b, vt_b);

  // attention (output in-place over q); AQT=128 -> 1024 blocks (%8==0)
  attn_mfma<<<BATCH * NH * (SEQ / AQT), blk, 0, stream>>>(q_b, k_b, vt_b, msk, q_b);

  // phase B: wo -> dead k region; o-proj + residual(x) -> x1 = d_out (fp32)
  cvt_f2b<<<nw / 1024, blk, 0, stream>>>(w_o, wo16, nw);
  dim3 gN1024(D_MODEL / 128, NROWS / 128);  // (8, 64) = 512 blocks
  gemm_bt<<<gN1024, blk, 0, stream>>>(q_b, wo16, D_MODEL, D_MODEL, D_MODEL, D_MODEL,
                                      nullptr, 0, x, nullptr, outf, nullptr,
                                      nullptr, nullptr, nullptr);

  // phase C: w1/w2 -> dead ao region; LN2 -> dead vt region; chunked FFN
  cvt_f2b<<<nf / 1024, blk, 0, stream>>>(w1, w116, nf);
  cvt_f2b<<<nf / 1024, blk, 0, stream>>>(w2, w216, nf);
  ln_kernel<<<NROWS, blk, 0, stream>>>(outf, g2, be2, ln2b);
  for (int c = 0; c < NCHUNK; c++) {
    const size_t ro = (size_t)c * CHUNK;
    dim3 g1c(DFF / 128,     CHUNK / 128);      // (32, 16) = 512 blocks
    dim3 g2c(D_MODEL / 128, CHUNK / 128, 4);   // (8, 16, 4): xy=128 blocks, split-K
    gemm_bt<<<g1c, blk, 0, stream>>>(ln2b + ro * D_MODEL, w116, D_MODEL, DFF,
                                     D_MODEL, D_MODEL, b1, 1,
                                     nullptr, hffc, nullptr, nullptr,
                                     nullptr, nullptr, nullptr);
    // FFN2 split-K=4 (K=1024 each): outf already holds x1 (residual) in place;
    // partials accumulate via device-scope fp32 atomics, bias from split 0.
    gemm_bt<<<g2c, blk, 0, stream>>>(hffc, w216, DFF / 4, D_MODEL, DFF, DFF, b2, 0,
                                     nullptr, nullptr, nullptr, outf + ro * D_MODEL,
                                     nullptr, nullptr, nullptr);
  }
}